// Round 1
// 114.456 us; speedup vs baseline: 1.3077x; 1.3077x over previous
//
#include <hip/hip_runtime.h>
#include <hip/hip_bf16.h>

#define NQ    8
#define HID   768
#define BATCH 8192
#define SPB   4                      // samples per block (1 per wave)
#define NBLK  (BATCH / SPB)          // 2048
#define TPB   256

// ---------- dtype-generic load/store ----------
template<int BF> __device__ __forceinline__ float LDV(const void* p, int i) {
    if constexpr (BF) return __bfloat162float(((const __hip_bfloat16*)p)[i]);
    else return ((const float*)p)[i];
}
template<int BF> __device__ __forceinline__ void STV(void* p, int i, float v) {
    if constexpr (BF) ((__hip_bfloat16*)p)[i] = __float2bfloat16(v);
    else ((float*)p)[i] = v;
}
// load 4 consecutive elements [4*i4 .. 4*i4+3] as float4
template<int BF> __device__ __forceinline__ float4 LD4(const void* p, int i4) {
    if constexpr (BF) {
        ushort4 v = ((const ushort4*)p)[i4];
        float4 r;
        r.x = __uint_as_float(((unsigned)v.x) << 16);
        r.y = __uint_as_float(((unsigned)v.y) << 16);
        r.z = __uint_as_float(((unsigned)v.z) << 16);
        r.w = __uint_as_float(((unsigned)v.w) << 16);
        return r;
    } else {
        return ((const float4*)p)[i4];
    }
}

// ws layout: int flag at byte 0; float qc[32] at byte 16 (DA,DB,Kre,Kim per qubit)

// ---------- setup: dtype sniff + per-qubit circuit constants ----------
__global__ void setup_kernel(const void* hidden, const void* wry, const void* wrz, void* ws) {
    __shared__ int votes;
    __shared__ int sFlag;
    int tid = threadIdx.x;
    if (tid == 0) votes = 0;
    __syncthreads();
    const unsigned int* hw = (const unsigned int*)hidden;
    int cnt = 0;
    #pragma unroll
    for (int k = 0; k < 16; ++k) {
        unsigned int w = hw[tid * 16 + k];
        unsigned int lo = w & 0xffffu;
        unsigned int e = (lo >> 7) & 0xffu;
        if (lo == 0u || (e >= 100u && e <= 133u)) cnt++;
    }
    atomicAdd(&votes, cnt);
    __syncthreads();
    if (tid == 0) {
        sFlag = (votes * 2 > TPB * 16) ? 1 : 0;
        *(int*)ws = sFlag;
    }
    __syncthreads();
    const int flag = sFlag;
    if (tid < NQ) {
        float ry0, ry1, rz0, rz1;
        if (flag) {
            ry0 = LDV<1>(wry, tid);  ry1 = LDV<1>(wry, NQ + tid);
            rz0 = LDV<1>(wrz, tid);  rz1 = LDV<1>(wrz, NQ + tid);
        } else {
            ry0 = LDV<0>(wry, tid);  ry1 = LDV<0>(wry, NQ + tid);
            rz0 = LDV<0>(wrz, tid);  rz1 = LDV<0>(wrz, NQ + tid);
        }
        float cA = cosf(0.5f*ry0), sA = sinf(0.5f*ry0);
        float cB = cosf(0.5f*ry1), sB = sinf(0.5f*ry1);
        float p0c = cosf(0.5f*rz0), p0s = sinf(0.5f*rz0);
        float p1c = cosf(0.5f*rz1), p1s = sinf(0.5f*rz1);
        // G1 = RZ0 * RY0
        float g00r =  cA*p0c, g00i = -cA*p0s;
        float g01r = -sA*p0c, g01i =  sA*p0s;
        float g10r =  sA*p0c, g10i =  sA*p0s;
        float g11r =  cA*p0c, g11i =  cA*p0s;
        // G2 = RY1 * G1
        float h00r = cB*g00r - sB*g10r, h00i = cB*g00i - sB*g10i;
        float h01r = cB*g01r - sB*g11r, h01i = cB*g01i - sB*g11i;
        float h10r = sB*g00r + cB*g10r, h10i = sB*g00i + cB*g10i;
        float h11r = sB*g01r + cB*g11r, h11i = sB*g01i + cB*g11i;
        // G3 = RZ1 * G2
        float f00r = h00r*p1c + h00i*p1s, f00i = h00i*p1c - h00r*p1s;
        float f01r = h01r*p1c + h01i*p1s, f01i = h01i*p1c - h01r*p1s;
        float f10r = h10r*p1c - h10i*p1s, f10i = h10i*p1c + h10r*p1s;
        float f11r = h11r*p1c - h11i*p1s, f11i = h11i*p1c + h11r*p1s;
        float DA = f00r*f00r + f00i*f00i - (f10r*f10r + f10i*f10i);
        float DB = f01r*f01r + f01i*f01i - (f11r*f11r + f11i*f11i);
        float Kr = (f00r*f01r + f00i*f01i) - (f10r*f11r + f10i*f11i);
        float Ki = (f00i*f01r - f00r*f01i) - (f10i*f11r - f10r*f11i);
        float* qc = (float*)((char*)ws + 16);
        qc[tid*4+0] = DA; qc[tid*4+1] = DB; qc[tid*4+2] = Kr; qc[tid*4+3] = Ki;
    }
}

// ---------- fused main: 1 wave per sample, qubit-distributed lanes ----------
// lane = 8*j + u : group j (lanes 8j..8j+7) owns qubit j; sublane u owns
// columns c = 4*(u + 8*t), t = 0..23  (each group covers all 768 columns).
template<int BF>
__device__ __forceinline__ void run_all(
    const void* hidden_, const void* W_in_, const void* b_in_,
    const void* W_out_, const void* b_out_, const void* gamma_, const void* beta_,
    void* out_, const float* qc)
{
    const int tid  = threadIdx.x;
    const int lane = tid & 63;
    const int wv   = tid >> 6;
    const int b    = blockIdx.x * SPB + wv;
    const int j    = lane >> 3;       // qubit group
    const int u    = lane & 7;        // sublane within group
    const int rowbase = b * HID;

    // ---- phase A: zz_j = <hidden_b, W_in_j>  (group j computes qubit j) ----
    float a0 = 0.f, a1 = 0.f, a2 = 0.f, a3 = 0.f;
    const int hbase = b * (HID/4);    // float4 index base of hidden row
    const int wbase = j * (HID/4);    // float4 index base of W_in row j
    #pragma unroll
    for (int t = 0; t < 24; ++t) {
        int i4 = u + (t << 3);
        float4 h = LD4<BF>(hidden_, hbase + i4);
        float4 w = LD4<BF>(W_in_,  wbase + i4);
        a0 = fmaf(h.x, w.x, a0); a1 = fmaf(h.y, w.y, a1);
        a2 = fmaf(h.z, w.z, a2); a3 = fmaf(h.w, w.w, a3);
    }
    float acc = (a0 + a1) + (a2 + a3);
    // reduce across the 8 sublanes of this group (bits 0..2)
    acc += __shfl_xor(acc, 1, 64);
    acc += __shfl_xor(acc, 2, 64);
    acc += __shfl_xor(acc, 4, 64);

    // ---- circuit: each group does ONE tanh/sinpi/cospi ----
    float zb = acc + LDV<BF>(b_in_, j);
    float th = tanhf(zb);             // theta = pi * th
    float sj = sinpif(th);
    float cj = cospif(th);

    float4 q = ((const float4*)qc)[j];      // DA, DB, Kr, Ki for qubit j
    float DA = q.x, DB = q.y, Kr = q.z, Ki = q.w;
    float ca = 0.5f * (DA + DB), da = 0.5f * (DA - DB);
    float uu = da * cj;
    float vv = fmaf(Kr, sj, ca);
    const bool g0 = (j == 0);
    // group 0 contributes identity to the j=1..7 products
    float MA = g0 ? 1.f : (vv + uu);
    float MB = g0 ? 1.f : (vv - uu);
    float fr = g0 ? 1.f : Kr;
    float fi = g0 ? 0.f : (cj * Ki);
    // butterfly products across the 8 groups (bits 3..5)
    #pragma unroll
    for (int d = 8; d < 64; d <<= 1) {
        MA *= __shfl_xor(MA, d, 64);
        MB *= __shfl_xor(MB, d, 64);
        float qr = __shfl_xor(fr, d, 64);
        float qi = __shfl_xor(fi, d, 64);
        float nr = fr * qr - fi * qi;
        float ni = fr * qi + fi * qr;
        fr = nr; fi = ni;
    }
    // broadcast qubit-0 quantities from lane 0
    float cc0 = __shfl(cj, 0, 64);
    float sc0 = __shfl(sj, 0, 64);
    float DA0 = __shfl(DA, 0, 64);
    float DB0 = __shfl(DB, 0, 64);
    float Kr0 = __shfl(Kr, 0, 64);
    float Ki0 = __shfl(Ki, 0, 64);
    float meas0 = 0.5f * (1.f + cc0) * DA0 * MA
                + 0.5f * (1.f - cc0) * DB0 * MB
                + sc0 * (Kr0 * fr - Ki0 * fi);
    float measj = g0 ? meas0 : fmaf(cc0, uu, vv);
    // all-gather meas (group jj's value lives in lane 8*jj)
    float m0 = meas0;
    float m1 = __shfl(measj,  8, 64);
    float m2 = __shfl(measj, 16, 64);
    float m3 = __shfl(measj, 24, 64);
    float m4 = __shfl(measj, 32, 64);
    float m5 = __shfl(measj, 40, 64);
    float m6 = __shfl(measj, 48, 64);
    float m7 = __shfl(measj, 56, 64);

    // ---- phase C: y = meas @ W_out^T + b_out, LayerNorm, store ----
    float yv[12];
    float sum = 0.f, sumsq = 0.f;
    #pragma unroll
    for (int t = 0; t < 12; ++t) {
        int h = lane + (t << 6);
        float4 w0 = LD4<BF>(W_out_, h * 2);       // W_out[h][0..3]
        float4 w1 = LD4<BF>(W_out_, h * 2 + 1);   // W_out[h][4..7]
        float y = LDV<BF>(b_out_, h);
        y = fmaf(m0, w0.x, y); y = fmaf(m1, w0.y, y);
        y = fmaf(m2, w0.z, y); y = fmaf(m3, w0.w, y);
        y = fmaf(m4, w1.x, y); y = fmaf(m5, w1.y, y);
        y = fmaf(m6, w1.z, y); y = fmaf(m7, w1.w, y);
        yv[t] = y;
        sum += y;
        sumsq = fmaf(y, y, sumsq);
    }
    #pragma unroll
    for (int d = 1; d < 64; d <<= 1) {
        sum   += __shfl_xor(sum,   d, 64);
        sumsq += __shfl_xor(sumsq, d, 64);
    }
    float mean = sum * (1.f / HID);
    float var  = fmaf(sumsq, 1.f / HID, -mean * mean);
    float rstd = rsqrtf(var + 1e-5f);
    #pragma unroll
    for (int t = 0; t < 12; ++t) {
        int h = lane + (t << 6);
        float g  = LDV<BF>(gamma_, h);
        float be = LDV<BF>(beta_,  h);
        float o  = fmaf((yv[t] - mean) * rstd, g, be);
        STV<BF>(out_, rowbase + h, o);
    }
}

__global__ __launch_bounds__(TPB, 4) void main_kernel(
    const void* hidden_, const void* W_in_, const void* b_in_,
    const void* W_out_, const void* b_out_, const void* gamma_, const void* beta_,
    void* out_, const void* ws_)
{
    const int flag = *(const int*)ws_;
    const float* qc = (const float*)((const char*)ws_ + 16);
    if (flag)
        run_all<1>(hidden_, W_in_, b_in_, W_out_, b_out_, gamma_, beta_, out_, qc);
    else
        run_all<0>(hidden_, W_in_, b_in_, W_out_, b_out_, gamma_, beta_, out_, qc);
}

extern "C" void kernel_launch(void* const* d_in, const int* in_sizes, int n_in,
                              void* d_out, int out_size, void* d_ws, size_t ws_size,
                              hipStream_t stream) {
    const void* hidden = d_in[0];
    const void* W_in   = d_in[1];
    const void* b_in   = d_in[2];
    const void* W_out  = d_in[3];
    const void* b_out  = d_in[4];
    const void* wry    = d_in[5];
    const void* wrz    = d_in[6];
    const void* gamma  = d_in[7];
    const void* beta   = d_in[8];
    setup_kernel<<<1, TPB, 0, stream>>>(hidden, wry, wrz, d_ws);
    main_kernel<<<NBLK, TPB, 0, stream>>>(hidden, W_in, b_in, W_out, b_out,
                                          gamma, beta, d_out, d_ws);
}